// Round 18
// baseline (43.498 us; speedup 1.0000x reference)
//
#include <hip/hip_runtime.h>
#include <hip/hip_bf16.h>

#define SEQ    2048
#define NHEAD  16
#define RPH    512          // rows per head = B*D
#define BK     64
#define NTH    256          // 4 waves: wave tb = col quarter of the quad

#define WSTRIDE 2184        // elems per wrev copy; 2184 % 64 == 8 (bank spread)
#define ABUF_E  2048        // elems per A buffer (32 rows x 64 cols bf16)
#define WCOP_E  (8 * ABUF_E)             // wcop after the EIGHT A buffers
#define TOT_E   (WCOP_E + 8 * WSTRIDE)   // 16384 + 17472 = 33856 elems (67712 B)
// wbase staging (guard 0..7, data 8..2055, zero pad 2056..2215) aliases abufs

typedef float  f32x16 __attribute__((ext_vector_type(16)));
typedef __bf16 bf16x8 __attribute__((ext_vector_type(8)));

struct PF { float4 v0, v1; };

__device__ __forceinline__ unsigned f2bf(float f) {
    union { __hip_bfloat16 h; unsigned short u; } cv;
    cv.h = __float2bfloat16(f);
    return (unsigned)cv.u;
}

__device__ __forceinline__ uint4 pack8u(float4 a, float4 b) {
    union { bf16x8 v; uint4 u; } r;
    r.v[0] = (__bf16)a.x; r.v[1] = (__bf16)a.y;
    r.v[2] = (__bf16)a.z; r.v[3] = (__bf16)a.w;
    r.v[4] = (__bf16)b.x; r.v[5] = (__bf16)b.y;
    r.v[6] = (__bf16)b.z; r.v[7] = (__bf16)b.w;
    return r.u;
}

#define MFMA32(a, b, c) __builtin_amdgcn_mfma_f32_32x32x16_bf16((a), (b), (c), 0, 0, 0)

// Load this thread's 1 staged row x 8 cols fp32 of chunk CH
// (block stages 32 rows: tid>>3 = row, (tid&7)*8 = col base).
#define LOADPF(P, CH)                                                         \
  { const float* g_ = Xp + (size_t)(CH) * BK;                                 \
    P.v0 = *(const float4*)g_;                                                \
    P.v1 = *(const float4*)(g_ + 4); }

// Pack+write this thread's staged row-slice into buffer AB (XOR-swizzled).
#define WRITEA(AB, P)  { *(uint4*)((AB) + wb0) = pack8u(P.v0, P.v1); }

// One K=16 step of mfma_32x32x16: one A frag (row=lane&31, 8 k-consecutive
// at k = 16*KS + 8*(lane>>5)), 4 MFMAs over the wave's 4 col-tiles of 32.
// B word for (KS, c) = 4ch + KS - 2c -> slot (P + KS - 2c) & 15.
#define KSTEP32(ABC, KS, P)                                                   \
  { bf16x8 af = *(const bf16x8*)((ABC) + ArowA + ((32 * (KS) + kq16) ^ swz)); \
    acc[0] = MFMA32(af, bw[((P)+(KS)-0)&15], acc[0]);                         \
    acc[1] = MFMA32(af, bw[((P)+(KS)-2)&15], acc[1]);                         \
    acc[2] = MFMA32(af, bw[((P)+(KS)-4)&15], acc[2]);                         \
    acc[3] = MFMA32(af, bw[((P)+(KS)-6)&15], acc[3]); }

// One SUPERCHUNK = chunks CH, CH+1. Counted-wait pipeline (r17 structure):
// MFMA from C0,C1 (staged 2 supers ago); window refills 4 words per chunk
// (slots provably stale); stage writes for CH+4,CH+5 issued LAST; barrier
// waits lgkmcnt(2) so the 2 fresh writes stay in flight across it.
#define SUPER(CH, P, C0, C1, N0, N1)                                          \
  {                                                                           \
    if ((CH) < nchw) {                                                        \
      __builtin_amdgcn_s_setprio(1);                                          \
      KSTEP32(C0, 0, P);                                                      \
      KSTEP32(C0, 1, P);                                                      \
      KSTEP32(C0, 2, P);                                                      \
      KSTEP32(C0, 3, P);                                                      \
      __builtin_amdgcn_s_setprio(0);                                          \
    }                                                                         \
    if ((CH) + 1 < nchw) {                                                    \
      bw[((P)+4)&15] = *(const bf16x8*)(wcB + 64 * (CH) + 64);                \
      bw[((P)+5)&15] = *(const bf16x8*)(wcB + 64 * (CH) + 80);                \
      bw[((P)+6)&15] = *(const bf16x8*)(wcB + 64 * (CH) + 96);                \
      bw[((P)+7)&15] = *(const bf16x8*)(wcB + 64 * (CH) + 112);               \
      __builtin_amdgcn_s_setprio(1);                                          \
      KSTEP32(C1, 0, (P) + 4);                                                \
      KSTEP32(C1, 1, (P) + 4);                                                \
      KSTEP32(C1, 2, (P) + 4);                                                \
      KSTEP32(C1, 3, (P) + 4);                                                \
      __builtin_amdgcn_s_setprio(0);                                          \
    }                                                                         \
    if ((CH) + 2 < nchw) {                                                    \
      bw[((P)+8)&15]  = *(const bf16x8*)(wcB + 64 * (CH) + 128);              \
      bw[((P)+9)&15]  = *(const bf16x8*)(wcB + 64 * (CH) + 144);              \
      bw[((P)+10)&15] = *(const bf16x8*)(wcB + 64 * (CH) + 160);              \
      bw[((P)+11)&15] = *(const bf16x8*)(wcB + 64 * (CH) + 176);              \
    }                                                                         \
    WRITEA(N0, pfA);                       /* stage CH+4 (tail: inert) */     \
    WRITEA(N1, pfB);                       /* stage CH+5 (tail: inert) */     \
    if ((CH) + 6 < nch) LOADPF(pfA, (CH) + 6);                                \
    if ((CH) + 7 < nch) LOADPF(pfB, (CH) + 7);                                \
    asm volatile("s_waitcnt lgkmcnt(2)\n\ts_barrier" ::: "memory");           \
  }

__global__ __launch_bounds__(NTH, 2) void mixer_kernel(
    const float* __restrict__ x, const float* __restrict__ wgt,
    const float* __restrict__ bias, float* __restrict__ out)
{
    __shared__ unsigned short smem[TOT_E] __attribute__((aligned(16)));
    char* b0 = (char*)smem;                     // A buffers (chunks mod 8)
    char* b1 = (char*)smem + ABUF_E * 2;
    char* b2 = (char*)smem + ABUF_E * 4;
    char* b3 = (char*)smem + ABUF_E * 6;
    char* b4 = (char*)smem + ABUF_E * 8;
    char* b5 = (char*)smem + ABUF_E * 10;
    char* b6 = (char*)smem + ABUF_E * 12;
    char* b7 = (char*)smem + ABUF_E * 14;
    unsigned short* wc = smem + WCOP_E;         // 8 shifted reversed-w copies

    const int tid  = threadIdx.x;
    const int lane = tid & 63;
    const int tb   = tid >> 6;                  // 0..3: col quarter

    // ---- block decode: 512 uniform blocks (40 chunks each) ----
    // quad pair pc=0: q {3,0}; pc=1: q {2,1} -> perfectly equal work.
    const int bid  = blockIdx.x;               // 0..511
    const int m    = (bid & 7) + 8 * ((bid >> 3) & 1);
    const int rt   = (bid >> 4) & 15;          // row tile 0..15 (32 rows)
    const int pc   = bid >> 8;                 // pair class
    const int qA   = pc ? 2 : 3;
    const int qB   = pc ? 1 : 0;

    const float* Xb = x   + (size_t)(m * RPH + rt * 32) * SEQ;
    float*       Ob = out + (size_t)(m * RPH + rt * 32) * SEQ;
    const float* wr = wgt  + m * SEQ;
    const float* br = bias + m * SEQ;

    // ---- staging map: thread stages 1 row-slice of the 32-row A tile ----
    const int srow = tid >> 3;                 // 0..31
    const int wsw  = (srow & 7) << 4;
    const int wb0  = srow * 128 + (((tid & 7) * 16) ^ wsw);
    const float* Xp = Xb + (size_t)srow * SEQ + (tid & 7) * 8;

    // ---- issue chunk-0/1 prefetch immediately (hides under prologue) ----
    PF pfA, pfB;
    LOADPF(pfA, 0);
    LOADPF(pfB, 1);

    // ---- phase 1: reversed bf16 weights into abuf-alias ----
    {
        const int t8 = tid * 8;                // 0..2040
        const float* g = wr + (2040 - t8);
        float4 lo = *(const float4*)g;
        float4 hi = *(const float4*)(g + 4);
        uint4 v;
        v.x = f2bf(hi.w) | (f2bf(hi.z) << 16);
        v.y = f2bf(hi.y) | (f2bf(hi.x) << 16);
        v.z = f2bf(lo.w) | (f2bf(lo.z) << 16);
        v.w = f2bf(lo.y) | (f2bf(lo.x) << 16);
        *(uint4*)(smem + 8 + t8) = v;
        if (tid < 21) {                        // guard (8) + pad (160)
            uint4 z = {0u, 0u, 0u, 0u};
            unsigned short* dst = (tid == 0) ? smem
                                 : smem + 8 + 2048 + (tid - 1) * 8;
            *(uint4*)dst = z;
        }
    }
    __syncthreads();

    // ---- phase 2: 8 shifted copies, vectorized: copy_c[i] = wbase[i-c] ----
    #pragma unroll
    for (int c = 0; c < 8; ++c) {
        for (int grp = tid; grp < WSTRIDE / 8; grp += NTH) {
            const int i = grp * 8;
            uint4 g0 = *(const uint4*)(smem + 8 + i - 8);
            uint4 g1 = *(const uint4*)(smem + 8 + i);
            unsigned d[9] = {g0.x, g0.y, g0.z, g0.w,
                             g1.x, g1.y, g1.z, g1.w, 0u};
            const int qd = (16 - 2 * c) >> 2;
            uint4 o;
            if (c & 1) {
                o.x = (d[qd]     >> 16) | (d[qd + 1] << 16);
                o.y = (d[qd + 1] >> 16) | (d[qd + 2] << 16);
                o.z = (d[qd + 2] >> 16) | (d[qd + 3] << 16);
                o.w = (d[qd + 3] >> 16) | (d[qd + 4] << 16);
            } else {
                o.x = d[qd];     o.y = d[qd + 1];
                o.z = d[qd + 2]; o.w = d[qd + 3];
            }
            *(uint4*)(wc + c * WSTRIDE + i) = o;
        }
    }
    __syncthreads();   // wcop ready; wbase alias (abufs) free to overwrite

    // ---- per-lane MFMA constants (32x32x16 fragment mapping) ----
    const int col_low = lane & 31;             // A row / B col / C col
    const int kq2     = lane >> 5;             // k half: k = 16ks + 8*kq2 + j
    const int kq16    = kq2 * 16;              // byte offset of k half
    const int swz     = (lane & 7) << 4;
    const int cpy     = (col_low + 1) & 7;     // alignment class -> copy id
    const int BcBase  = cpy * WSTRIDE + cpy + 2047 - col_low + 8 * kq2;
    const int ArowA   = col_low * 128;

    // ---- two quads per block: qA (heavy) then qB ----
    for (int h = 0; h < 2; ++h) {
        const int q    = h ? qB : qA;
        const int nch  = 8 * q + 8;            // shared K sweep chunks (of 64)
        const int nchw = 8 * q + 2 * tb + 2;   // this wave's MFMA extent
        const int t0w  = 512 * q + 128 * tb;   // wave's col base
        const unsigned short* wcB = wc + (BcBase - t0w);

        if (h) { LOADPF(pfA, 0); LOADPF(pfB, 1); }  // same rows both quads

        // window prologue: words -6..3 into slots w&15 (chunk 0 needs -6..3)
        bf16x8 bw[16];
        #pragma unroll
        for (int w = -6; w <= 3; ++w)
            bw[w & 15] = *(const bf16x8*)(wcB + 16 * w);

        // seed superchunks 0,1 (chunks 0..3); pf -> chunks 4,5 (nch >= 8)
        WRITEA(b0, pfA);
        WRITEA(b1, pfB);
        LOADPF(pfA, 2);
        LOADPF(pfB, 3);
        WRITEA(b2, pfA);
        WRITEA(b3, pfB);
        LOADPF(pfA, 4);
        LOADPF(pfB, 5);
        asm volatile("s_waitcnt lgkmcnt(0)\n\ts_barrier" ::: "memory");

        f32x16 acc[4] = {};
        for (int ch = 0; ch < nch; ch += 8) {  // nch % 8 == 0 always
            SUPER(ch,     0, b0, b1, b4, b5);
            SUPER(ch + 2, 8, b2, b3, b6, b7);
            SUPER(ch + 4, 0, b4, b5, b0, b1);
            SUPER(ch + 6, 8, b6, b7, b2, b3);
        }

        // epilogue: C/D layout col=lane&31, row=(reg&3)+8*(reg>>2)+4*(lane>>5)
        #pragma unroll
        for (int c = 0; c < 4; ++c) {
            const int colg = t0w + 32 * c + col_low;
            const float bv = br[colg];
            #pragma unroll
            for (int reg = 0; reg < 16; ++reg) {
                const int row = (reg & 3) + 8 * (reg >> 2) + 4 * kq2;
                Ob[(size_t)row * SEQ + colg] = acc[c][reg] + bv;
            }
        }
        // next quad's prologue barrier (lgkmcnt 0) drains any in-flight
        // writes before its bodies read the reseeded buffers.
    }
}

extern "C" void kernel_launch(void* const* d_in, const int* in_sizes, int n_in,
                              void* d_out, int out_size, void* d_ws, size_t ws_size,
                              hipStream_t stream) {
    const float* x  = (const float*)d_in[0];
    const float* w  = (const float*)d_in[1];
    const float* bs = (const float*)d_in[2];
    float* out = (float*)d_out;
    dim3 grid(512);    // 16 heads x 16 row tiles x 2 quad-pair classes
    dim3 block(NTH);
    hipLaunchKernelGGL(mixer_kernel, grid, block, 0, stream, x, w, bs, out);
}